// Round 1
// baseline (170.611 us; speedup 1.0000x reference)
//
#include <hip/hip_runtime.h>

#define T_ 12
#define N_ 1370
#define MSEQ 64      // sequences per block (4 MFMA n-tiles per wave)
#define NT 4         // seq tiles per wave
#define LDA 72       // h LDS row stride in shorts (144B -> 2-way banks max, free)
#define NBLK 1370    // 87680 / 64

typedef __attribute__((ext_vector_type(8))) short short8;
typedef __attribute__((ext_vector_type(4))) float floatx4;
typedef __attribute__((ext_vector_type(4))) unsigned uint4v;
typedef __attribute__((ext_vector_type(2))) unsigned uint2v;

#define NLOG2E -1.4426950408889634f
#define TLOG2E 2.8853900817779268f
#define N2LOG2E -5.7707801635558536f   // -2*TLOG2E

__device__ __forceinline__ short f2bf(float x) {
  unsigned u = __builtin_bit_cast(unsigned, x);
  u = (u + 0x7fffu + ((u >> 16) & 1u)) >> 16;
  return (short)u;
}
// HW packed f32->bf16 (RNE): low16 = bf16(a), high16 = bf16(b)
__device__ __forceinline__ unsigned pk_bf16(float a, float b) {
  unsigned r;
  asm("v_cvt_pk_bf16_f32 %0, %1, %2" : "=v"(r) : "v"(a), "v"(b));
  return r;
}
__device__ __forceinline__ short8 load_w8s(const float* __restrict__ p, float s) {
  floatx4 a = *(const floatx4*)p;
  floatx4 b = *(const floatx4*)(p + 4);
  uint4v u = {pk_bf16(a[0] * s, a[1] * s), pk_bf16(a[2] * s, a[3] * s),
              pk_bf16(b[0] * s, b[1] * s), pk_bf16(b[2] * s, b[3] * s)};
  return __builtin_bit_cast(short8, u);
}

// Block = 64 seqs, 4 waves; each wave owns 16 gate-unit rows (urow) and
// iterates 4 seq-tiles (nt) -> 16 independent cell chains/wave for latency
// hiding, and half the barrier count per sequence vs MSEQ=32.
// Swapped MFMA roles: A = weights (m = gate unit), B = [h | x | 1] (n = seq).
// k layout: 0..63 = h, 64..71 = x (q==0 A-lanes), 72 = bias (q==1, j==0);
// B chunk2: q==0 lanes read x row, q>=1 lanes broadcast-read the shared
// ones_row (only element 0 = 1.0 matters; matching A rows are zero).
// D: col=lane&15 = seq, row=q*4+r = unit -> h writeback one ds_write_b64.
// Activation scales pre-folded into weights: i,f,o rows by -log2e
// (sigma = 1/(1+2^y)), g rows by 2*log2e (tanh = 1 - 2/(1+2^z)).
// Cell state carried pre-scaled by 2*log2e: cs = fv*cs + (dg-2)*T*rp*df*dq,
// so tanh(c) = 1 - 2/(1+2^cs) needs no extra scale mul.
__global__ void __launch_bounds__(256, 4) lstm_kernel(
    const float* __restrict__ x, const float* __restrict__ W_ih,
    const float* __restrict__ W_hh, const float* __restrict__ b_ih,
    const float* __restrict__ b_hh, const float* __restrict__ W_fc,
    const float* __restrict__ b_fc, float* __restrict__ out) {
  __shared__ short hbuf[2][MSEQ][LDA];
  __shared__ __align__(16) short xbuf[T_][MSEQ][8];
  __shared__ __align__(16) short ones_row[8];

  const int tid = threadIdx.x;
  const int wave = tid >> 6;
  const int lane = tid & 63;
  const int m16 = lane & 15;
  const int q = lane >> 4;
  const int blk = blockIdx.x;

  // ---- A-operand weight fragments: lane row = unit wave*16+m16 ----
  const int urow = wave * 16 + m16;
  short8 wA[4][3];
#pragma unroll
  for (int g = 0; g < 4; ++g) {
    const float sg = (g == 2) ? TLOG2E : NLOG2E;
    const int grow = g * 64 + urow;
    const float* wr = W_hh + grow * 64;
    wA[g][0] = load_w8s(wr + q * 8, sg);
    wA[g][1] = load_w8s(wr + 32 + q * 8, sg);
    short8 z = {0, 0, 0, 0, 0, 0, 0, 0};
    if (q == 0) {
      wA[g][2] = load_w8s(W_ih + grow * 8, sg);  // k=64..71: x columns
    } else if (q == 1) {
      z[0] = f2bf(sg * (b_ih[grow] + b_hh[grow]));  // k=72: bias column
      wA[g][2] = z;
    } else {
      wA[g][2] = z;  // k=80..95 dead
    }
  }

  // ---- zero hbuf (h0 = 0, pads = 0); write the shared ones row ----
  {
    int* hp = (int*)hbuf;
#pragma unroll
    for (int i = tid; i < (2 * MSEQ * LDA) / 2; i += 256) hp[i] = 0;
    if (tid < 8) ones_row[tid] = (tid == 0) ? (short)0x3F80 : (short)0;
  }

  // ---- stage all 12 timesteps of x as bf16: float4 load + cvt_pk ----
  {
#pragma unroll
    for (int j = 0; j < 6; ++j) {
      const int slot = j * 256 + tid;   // 12t * 64seq * 2half = 1536 slots
      const int t = slot >> 7;
      const int idx = slot & 127;
      const int seq = idx >> 1;
      const int half = idx & 1;
      const int s0 = blk * MSEQ + seq;
      const int bidx = s0 / N_;
      const int nidx = s0 - bidx * N_;
      const floatx4 v = *(const floatx4*)(
          x + (((size_t)bidx * T_ + t) * N_ + nidx) * 8 + half * 4);
      uint2v u = {pk_bf16(v[0], v[1]), pk_bf16(v[2], v[3])};
      *(uint2v*)&xbuf[t][seq][half * 4] = u;
    }
  }
  __syncthreads();

  const floatx4 zacc = {0.0f, 0.0f, 0.0f, 0.0f};

  float cst[NT][4];
#pragma unroll
  for (int nt = 0; nt < NT; ++nt)
#pragma unroll
    for (int r = 0; r < 4; ++r) cst[nt][r] = 0.0f;

  for (int t = 0; t < T_; ++t) {
    const int rb = t & 1, wb = rb ^ 1;
#pragma unroll
    for (int nt = 0; nt < NT; ++nt) {
      const int srow = nt * 16 + m16;
      short8 b0 = *(const short8*)&hbuf[rb][srow][q * 8];
      short8 b1 = *(const short8*)&hbuf[rb][srow][32 + q * 8];
      const short* bxp = q ? &ones_row[0] : &xbuf[t][srow][0];
      short8 bx = *(const short8*)bxp;
      floatx4 gi = __builtin_amdgcn_mfma_f32_16x16x32_bf16(wA[0][0], b0, zacc, 0, 0, 0);
      floatx4 gf = __builtin_amdgcn_mfma_f32_16x16x32_bf16(wA[1][0], b0, zacc, 0, 0, 0);
      floatx4 gg = __builtin_amdgcn_mfma_f32_16x16x32_bf16(wA[2][0], b0, zacc, 0, 0, 0);
      floatx4 go = __builtin_amdgcn_mfma_f32_16x16x32_bf16(wA[3][0], b0, zacc, 0, 0, 0);
      gi = __builtin_amdgcn_mfma_f32_16x16x32_bf16(wA[0][1], b1, gi, 0, 0, 0);
      gf = __builtin_amdgcn_mfma_f32_16x16x32_bf16(wA[1][1], b1, gf, 0, 0, 0);
      gg = __builtin_amdgcn_mfma_f32_16x16x32_bf16(wA[2][1], b1, gg, 0, 0, 0);
      go = __builtin_amdgcn_mfma_f32_16x16x32_bf16(wA[3][1], b1, go, 0, 0, 0);
      gi = __builtin_amdgcn_mfma_f32_16x16x32_bf16(wA[0][2], bx, gi, 0, 0, 0);
      gf = __builtin_amdgcn_mfma_f32_16x16x32_bf16(wA[1][2], bx, gf, 0, 0, 0);
      gg = __builtin_amdgcn_mfma_f32_16x16x32_bf16(wA[2][2], bx, gg, 0, 0, 0);
      go = __builtin_amdgcn_mfma_f32_16x16x32_bf16(wA[3][2], bx, go, 0, 0, 0);
      float hv[4];
#pragma unroll
      for (int r = 0; r < 4; ++r) {
        float di = 1.0f + __builtin_amdgcn_exp2f(gi[r]);
        float df = 1.0f + __builtin_amdgcn_exp2f(gf[r]);
        float dg = 1.0f + __builtin_amdgcn_exp2f(gg[r]);
        float dq = 1.0f + __builtin_amdgcn_exp2f(go[r]);
        float pa = di * df, pb = dg * dq;
        float rp = __builtin_amdgcn_rcpf(pa * pb);
        float fv = rp * di * pb;                       // 1/df = f
        float rpa = rp * pa;
        float ov = rpa * dg;                           // 1/dq = o
        float tg = fmaf(TLOG2E, dg, N2LOG2E);          // (dg-2)*2log2e
        float ig = tg * rp * (df * dq);                // i*g*2log2e
        float cs = fmaf(fv, cst[nt][r], ig);           // c*2log2e
        cst[nt][r] = cs;
        float dt = 1.0f + __builtin_amdgcn_exp2f(cs);
        float tc = fmaf(-2.0f, __builtin_amdgcn_rcpf(dt), 1.0f);  // tanh(c)
        hv[r] = ov * tc;
      }
      // one b64 write: h for seq srow, units wave*16+q*4 .. +3
      unsigned long long pk =
          (unsigned long long)pk_bf16(hv[0], hv[1]) |
          ((unsigned long long)pk_bf16(hv[2], hv[3]) << 32);
      *(unsigned long long*)&hbuf[wb][srow][wave * 16 + q * 4] = pk;
    }
    __syncthreads();
  }

  // ---- final FC: y = h_T @ W_fc^T + b_fc; h_T is in hbuf[0] ----
  {
    short8 f0, f1;
    short8 z = {0, 0, 0, 0, 0, 0, 0, 0};
    if (m16 < 8) {
      const float* wr = W_fc + m16 * 64;
      f0 = load_w8s(wr + q * 8, 1.0f);
      f1 = load_w8s(wr + 32 + q * 8, 1.0f);
    } else {
      f0 = z;
      f1 = z;
    }
    const int srow = wave * 16 + m16;  // each wave handles its 16 seqs
    short8 h0 = *(const short8*)&hbuf[0][srow][q * 8];
    short8 h1 = *(const short8*)&hbuf[0][srow][32 + q * 8];
    floatx4 acc = __builtin_amdgcn_mfma_f32_16x16x32_bf16(f0, h0, zacc, 0, 0, 0);
    acc = __builtin_amdgcn_mfma_f32_16x16x32_bf16(f1, h1, acc, 0, 0, 0);
    if (q < 2) {
      const int orow = blk * MSEQ + srow;
#pragma unroll
      for (int r = 0; r < 4; ++r)
        out[orow * 8 + q * 4 + r] = acc[r] + b_fc[q * 4 + r];
    }
  }
}

extern "C" void kernel_launch(void* const* d_in, const int* in_sizes, int n_in,
                              void* d_out, int out_size, void* d_ws,
                              size_t ws_size, hipStream_t stream) {
  const float* x    = (const float*)d_in[0];
  const float* W_ih = (const float*)d_in[1];
  const float* W_hh = (const float*)d_in[2];
  const float* b_ih = (const float*)d_in[3];
  const float* b_hh = (const float*)d_in[4];
  const float* W_fc = (const float*)d_in[5];
  const float* b_fc = (const float*)d_in[6];
  float* out = (float*)d_out;
  hipLaunchKernelGGL(lstm_kernel, dim3(NBLK), dim3(256), 0, stream,
                     x, W_ih, W_hh, b_ih, b_hh, W_fc, b_fc, out);
}